// Round 11
// baseline (345.838 us; speedup 1.0000x reference)
//
#include <hip/hip_runtime.h>

typedef __attribute__((ext_vector_type(8))) short bf16x8;
typedef __attribute__((ext_vector_type(4))) float f32x4;

__device__ __forceinline__ unsigned short f2bf(float f) {
  unsigned int u = __float_as_uint(f);
  u += 0x7FFF + ((u >> 16) & 1);
  return (unsigned short)(u >> 16);
}

__device__ __forceinline__ void gload_lds16(const void* g, void* l) {
  __builtin_amdgcn_global_load_lds(
      (const __attribute__((address_space(1))) unsigned int*)g,
      (__attribute__((address_space(3))) unsigned int*)l,
      16, 0, 0);
}

#define MF(a, b, c) __builtin_amdgcn_mfma_f32_16x16x32_bf16((a), (b), (c), 0, 0, 0)
#define FENCE asm volatile("" ::: "memory")

// ---------------------------------------------------------------------------
// fused cast fp32 -> bf16 for x, w_attn, w_proj in one sweep
// ---------------------------------------------------------------------------
__global__ void cast_all(const float* __restrict__ x,
                         const float* __restrict__ wa,
                         const float* __restrict__ wp,
                         unsigned short* __restrict__ xb,
                         unsigned short* __restrict__ wab,
                         unsigned short* __restrict__ wpb,
                         int n1, int n2, int n4) {
  int stride = gridDim.x * blockDim.x;
  for (int i = blockIdx.x * blockDim.x + threadIdx.x; i < n4; i += stride) {
    const float4* src;
    ushort4* dst;
    int j;
    if (i < n1)      { src = (const float4*)x,  dst = (ushort4*)xb,  j = i; }
    else if (i < n2) { src = (const float4*)wa, dst = (ushort4*)wab, j = i - n1; }
    else             { src = (const float4*)wp, dst = (ushort4*)wpb, j = i - n2; }
    float4 v = src[j];
    ushort4 o;
    o.x = f2bf(v.x); o.y = f2bf(v.y); o.z = f2bf(v.z); o.w = f2bf(v.w);
    dst[j] = o;
  }
}

// ---------------------------------------------------------------------------
// 256x256 8-phase GEMM (round-8 schedule, verbatim — 146us, conflicts 0)
// ---------------------------------------------------------------------------
template<int EPI>
__global__ __launch_bounds__(512, 2)
void gemm8p(const unsigned short* __restrict__ A,
            const unsigned short* __restrict__ Bw,
            float* __restrict__ Cf,
            unsigned short* __restrict__ Qo,
            unsigned short* __restrict__ Ko,
            unsigned short* __restrict__ Vo,
            int M, int N, int K, int Lseq) {
  __shared__ unsigned short lds[2][2][2][8192];  // [A0/B1][dbuf][half][128x64]
  const int tid = threadIdx.x;
  const int lane = tid & 63, w = tid >> 6;
  const int wm = w >> 2, wn = w & 3;
  const int bh = wn >> 1;
  const int bcol = (wn & 1) * 64;
  const int g4 = lane >> 4, r16 = lane & 15;
  const long arow0 = (long)blockIdx.y * 256;
  const long brow0 = (long)blockIdx.x * 256;

#define LDA(db, mf, kk)                                                       \
  (*(const bf16x8*)((const char*)&lds[0][db][wm][0] +                         \
                    (((mf)*16 + r16) << 7) +                                  \
                    ((((kk)*4 + g4) ^ (r16 & 7)) << 4)))
#define LDB(db, nf, kk)                                                       \
  (*(const bf16x8*)((const char*)&lds[1][db][bh][0] +                         \
                    ((bcol + (nf)*16 + r16) << 7) +                           \
                    ((((kk)*4 + g4) ^ (r16 & 7)) << 4)))

#define STG(mat, db, half, kt)                                                \
  do {                                                                        \
    const unsigned short* g_ = (mat) ? Bw : A;                                \
    long r0_ = ((mat) ? brow0 : arow0) + (half)*128;                          \
    int k0_ = (kt) << 6;                                                      \
    _Pragma("unroll")                                                         \
    for (int c_ = 0; c_ < 2; ++c_) {                                          \
      int off_ = (c_ << 13) + (tid << 4);                                     \
      int row_ = off_ >> 7;                                                   \
      int scb_ = ((off_ >> 4) & 7) ^ (row_ & 7);                              \
      gload_lds16(g_ + (r0_ + row_) * (long)K + k0_ + scb_ * 8,               \
                  (char*)&lds[mat][db][half][0] + off_);                      \
    }                                                                         \
  } while (0)

  f32x4 acc[8][4];
#pragma unroll
  for (int i = 0; i < 8; ++i)
#pragma unroll
    for (int j = 0; j < 4; ++j) acc[i][j] = (f32x4){0.f, 0.f, 0.f, 0.f};

  bf16x8 b00, b01, b10, b11, b20, b21, b30, b31;

#define PH(db, q, STAGE_STMT, VMSTMT)                                         \
  do {                                                                        \
    bf16x8 a00 = LDA(db, 2*(q), 0), a01 = LDA(db, 2*(q), 1);                  \
    bf16x8 a10 = LDA(db, 2*(q)+1, 0), a11 = LDA(db, 2*(q)+1, 1);              \
    STAGE_STMT;                                                               \
    VMSTMT;                                                                   \
    FENCE; __builtin_amdgcn_s_barrier(); FENCE;                               \
    __builtin_amdgcn_s_setprio(1);                                            \
    acc[2*(q)][0] = MF(a00, b00, acc[2*(q)][0]);                              \
    acc[2*(q)][0] = MF(a01, b01, acc[2*(q)][0]);                              \
    acc[2*(q)][1] = MF(a00, b10, acc[2*(q)][1]);                              \
    acc[2*(q)][1] = MF(a01, b11, acc[2*(q)][1]);                              \
    acc[2*(q)][2] = MF(a00, b20, acc[2*(q)][2]);                              \
    acc[2*(q)][2] = MF(a01, b21, acc[2*(q)][2]);                              \
    acc[2*(q)][3] = MF(a00, b30, acc[2*(q)][3]);                              \
    acc[2*(q)][3] = MF(a01, b31, acc[2*(q)][3]);                              \
    acc[2*(q)+1][0] = MF(a10, b00, acc[2*(q)+1][0]);                          \
    acc[2*(q)+1][0] = MF(a11, b01, acc[2*(q)+1][0]);                          \
    acc[2*(q)+1][1] = MF(a10, b10, acc[2*(q)+1][1]);                          \
    acc[2*(q)+1][1] = MF(a11, b11, acc[2*(q)+1][1]);                          \
    acc[2*(q)+1][2] = MF(a10, b20, acc[2*(q)+1][2]);                          \
    acc[2*(q)+1][2] = MF(a11, b21, acc[2*(q)+1][2]);                          \
    acc[2*(q)+1][3] = MF(a10, b30, acc[2*(q)+1][3]);                          \
    acc[2*(q)+1][3] = MF(a11, b31, acc[2*(q)+1][3]);                          \
    __builtin_amdgcn_s_setprio(0);                                            \
    FENCE; __builtin_amdgcn_s_barrier(); FENCE;                               \
  } while (0)

#define LOADB(db)                                                             \
  do {                                                                        \
    b00 = LDB(db, 0, 0); b01 = LDB(db, 0, 1);                                 \
    b10 = LDB(db, 1, 0); b11 = LDB(db, 1, 1);                                 \
    b20 = LDB(db, 2, 0); b21 = LDB(db, 2, 1);                                 \
    b30 = LDB(db, 3, 0); b31 = LDB(db, 3, 1);                                 \
  } while (0)

#define VM4 asm volatile("s_waitcnt vmcnt(4)" ::: "memory")

  const int NT = K >> 6;
  STG(0, 0, 0, 0); STG(0, 0, 1, 0);
  STG(1, 0, 0, 0); STG(1, 0, 1, 0);
  STG(1, 1, 0, 1); STG(1, 1, 1, 1);
  VM4;
  FENCE; __builtin_amdgcn_s_barrier(); FENCE;

  for (int i = 0; i < (NT >> 1); ++i) {
    const int t1 = 2 * i + 1;
    int n0 = 2 * i + 2; if (n0 > NT - 1) n0 = NT - 1;
    int n1 = 2 * i + 3; if (n1 > NT - 1) n1 = NT - 1;
    LOADB(0);
    PH(0, 0, STG(0, 1, 0, t1), );        // ph1
    PH(0, 1, STG(0, 1, 1, t1), );        // ph2
    PH(0, 2, STG(1, 0, 0, n0), );        // ph3
    PH(0, 3, STG(1, 0, 1, n0), VM4);     // ph4
    LOADB(1);
    PH(1, 0, STG(0, 0, 0, n0), );        // ph5
    PH(1, 1, STG(0, 0, 1, n0), );        // ph6
    PH(1, 2, STG(1, 1, 0, n1), );        // ph7
    PH(1, 3, STG(1, 1, 1, n1), VM4);     // ph8
  }
  asm volatile("s_waitcnt vmcnt(0)" ::: "memory");

  const float qscale = 0.08838834764831845f;
#pragma unroll
  for (int mf = 0; mf < 8; ++mf) {
#pragma unroll
    for (int nf = 0; nf < 4; ++nf) {
#pragma unroll
      for (int i = 0; i < 4; ++i) {
        long row = arow0 + wm * 128 + mf * 16 + 4 * g4 + i;
        long col = brow0 + wn * 64 + nf * 16 + r16;
        float v = acc[mf][nf][i];
        if (EPI == 0) {
          Cf[row * N + col] = v;
        } else {
          int which = (int)(col >> 11);
          int h = ((int)col >> 7) & 15;
          int d = (int)col & 127;
          int b = (int)(row >> 11);
          int l = (int)row & 2047;
          long bhead = (long)(b * 16 + h);
          if (which == 0)
            Qo[(bhead * Lseq + l) * 128 + d] = f2bf(v * qscale);
          else if (which == 1)
            Ko[(bhead * Lseq + l) * 128 + d] = f2bf(v);
          else
            Vo[(bhead * 128 + d) * Lseq + l] = f2bf(v);
        }
      }
    }
  }
#undef LDA
#undef LDB
#undef STG
#undef PH
#undef LOADB
#undef VM4
}

// ---------------------------------------------------------------------------
// 2-phase 128x128 GEMM (proj). Known-correct.
// ---------------------------------------------------------------------------
template<int EPI>
__global__ __launch_bounds__(256, 4)
void gemm_bt(const unsigned short* __restrict__ A,
             const unsigned short* __restrict__ Bw,
             float* __restrict__ Cf,
             unsigned short* __restrict__ Qo,
             unsigned short* __restrict__ Ko,
             unsigned short* __restrict__ Vo,
             int M, int N, int K, int Lseq, int nbx) {
  __shared__ unsigned short As[2][128 * 32];
  __shared__ unsigned short Bs[2][128 * 32];
  const int tid = threadIdx.x;
  const int lane = tid & 63, w = tid >> 6;
  const int wm = w >> 1, wn = w & 1;
  const int g4 = lane >> 4, r16 = lane & 15;

  const int nwg = gridDim.x;
  const int cpx = nwg >> 3;
  const int bid = (blockIdx.x & 7) * cpx + (blockIdx.x >> 3);
  const long arow0 = (long)(bid / nbx) * 128;
  const long brow0 = (long)(bid % nbx) * 128;

#define STAGE_G(k0_, buf_)                                                    \
  do {                                                                        \
    _Pragma("unroll")                                                         \
    for (int c_ = 0; c_ < 2; ++c_) {                                          \
      int off_ = (w << 11) + (c_ << 10) + (lane << 4);                        \
      int row_ = off_ >> 6;                                                   \
      int cbs_ = ((off_ >> 4) & 3) ^ ((row_ >> 1) & 3);                       \
      gload_lds16(A + (arow0 + row_) * (long)K + (k0_) + cbs_ * 8,            \
                  (char*)As[buf_] + off_);                                    \
      gload_lds16(Bw + (brow0 + row_) * (long)K + (k0_) + cbs_ * 8,           \
                  (char*)Bs[buf_] + off_);                                    \
    }                                                                         \
  } while (0)

  f32x4 acc[4][4];
#pragma unroll
  for (int i = 0; i < 4; ++i)
#pragma unroll
    for (int j = 0; j < 4; ++j) acc[i][j] = (f32x4){0.f, 0.f, 0.f, 0.f};

  const int T = K >> 5;
  int cur = 0;
  STAGE_G(0, 0);

  for (int t = 0; t < T; ++t) {
    if (t < T - 1) {
      STAGE_G((t + 1) << 5, cur ^ 1);
      asm volatile("s_waitcnt vmcnt(4)" ::: "memory");
    } else {
      asm volatile("s_waitcnt vmcnt(0)" ::: "memory");
    }
    __builtin_amdgcn_s_barrier();

    const int rb = g4 ^ ((r16 >> 1) & 3);
    bf16x8 af[4], bf[4];
#pragma unroll
    for (int mf = 0; mf < 4; ++mf)
      af[mf] = *(const bf16x8*)((const char*)As[cur] +
                                ((64 * wm + 16 * mf + r16) << 6) + (rb << 4));
#pragma unroll
    for (int nf = 0; nf < 4; ++nf)
      bf[nf] = *(const bf16x8*)((const char*)Bs[cur] +
                                ((64 * wn + 16 * nf + r16) << 6) + (rb << 4));
#pragma unroll
    for (int mf = 0; mf < 4; ++mf)
#pragma unroll
      for (int nf = 0; nf < 4; ++nf)
        acc[mf][nf] = MF(af[mf], bf[nf], acc[mf][nf]);
    asm volatile("" ::: "memory");
    __builtin_amdgcn_s_barrier();
    cur ^= 1;
  }
#undef STAGE_G

  const float qscale = 0.08838834764831845f;
#pragma unroll
  for (int mf = 0; mf < 4; ++mf) {
#pragma unroll
    for (int nf = 0; nf < 4; ++nf) {
#pragma unroll
      for (int i = 0; i < 4; ++i) {
        long row = arow0 + 64 * wm + 16 * mf + 4 * g4 + i;
        long col = brow0 + 64 * wn + 16 * nf + r16;
        float v = acc[mf][nf][i];
        if (EPI == 0) {
          Cf[row * N + col] = v;
        } else {
          int which = (int)(col >> 11);
          int h = ((int)col >> 7) & 15;
          int d = (int)col & 127;
          int b = (int)(row >> 11);
          int l = (int)row & 2047;
          long bhead = (long)(b * 16 + h);
          if (which == 0)
            Qo[(bhead * Lseq + l) * 128 + d] = f2bf(v * qscale);
          else if (which == 1)
            Ko[(bhead * Lseq + l) * 128 + d] = f2bf(v);
          else
            Vo[(bhead * 128 + d) * Lseq + l] = f2bf(v);
        }
      }
    }
  }
}

// ---------------------------------------------------------------------------
// Flash attention (causal), QBLK=128, 8 waves. Q pre-scaled; RoPE = no-op.
// Same 2-phase K/V LDS pipeline as before, but each staged tile now feeds
// 128 q-rows (staging + barrier cost per work halved). Waves 0-3 skip the
// final kv-tile's compute via ktwave (barriers unconditional).
// Grid 512 = 32 bh x 16 qtiles, XCD-grouped, longest-first.
// ---------------------------------------------------------------------------
__global__ __launch_bounds__(512, 1)
void attn_fwd(const unsigned short* __restrict__ Q,
              const unsigned short* __restrict__ K,
              const unsigned short* __restrict__ Vt,
              unsigned short* __restrict__ Y, int L) {
  const int D = 128;
  const int id = blockIdx.x;
  const int g = id & 7, kk = id >> 3;          // 64 blocks per XCD group
  const int bh = (g << 2) + (kk >> 4);         // 4 heads per XCD
  const int qt2 = 15 - (kk & 15);              // longest first
  const int tid = threadIdx.x, lane = tid & 63, w = tid >> 6;
  const int g4 = lane >> 4, r16 = lane & 15;
  const int q0 = qt2 * 128;
  const int kthi = 2 * qt2 + 1;                              // last kv-tile
  const int ktwave = (q0 + 16 * w + 15) >> 6;                // per-wave bound

  __shared__ unsigned short Klds[2 * 64 * 128];   // 2 x 16KB
  __shared__ unsigned short Vlds[2 * 128 * 64];   // 2 x 16KB
  __shared__ unsigned short P[8][16][72];         // wave-private; +8 pad

  const unsigned short* Qh = Q + (long)bh * L * D;
  const unsigned short* Kh = K + (long)bh * L * D;
  const unsigned short* Vh = Vt + (long)bh * D * L;

  // 512 threads: 2 rounds of 8KB per matrix. LDS dest wave-uniform base
  // (w<<10) + (r<<13); global source pre-swizzled (cb ^= row&7 on 16B units).
#define STAGE_TILE(kt_, buf_)                                                 \
  do {                                                                        \
    const int kbase_ = (kt_) * 64;                                            \
    _Pragma("unroll")                                                         \
    for (int r_ = 0; r_ < 2; ++r_) {                                          \
      int off_ = (tid << 4) + (r_ << 13);                                     \
      int krow_ = off_ >> 8, kcb_ = (off_ >> 4) & 15;                         \
      int kcbs_ = kcb_ ^ (krow_ & 7);                                         \
      gload_lds16(Kh + (long)(kbase_ + krow_) * 128 + kcbs_ * 8,              \
                  (char*)Klds + (buf_)*16384 + (w << 10) + (r_ << 13));       \
      int vrow_ = off_ >> 7, vcb_ = (off_ >> 4) & 7;                          \
      int vcbs_ = vcb_ ^ (vrow_ & 7);                                         \
      gload_lds16(Vh + (long)vrow_ * L + kbase_ + vcbs_ * 8,                  \
                  (char*)Vlds + (buf_)*16384 + (w << 10) + (r_ << 13));       \
    }                                                                         \
  } while (0)

  bf16x8 qf[4];
  {
    long qrow = q0 + 16 * w + r16;
#pragma unroll
    for (int ks = 0; ks < 4; ++ks)
      qf[ks] = *(const bf16x8*)(Qh + qrow * D + ks * 32 + g4 * 8);
  }
  f32x4 o[8];
#pragma unroll
  for (int j = 0; j < 8; ++j) o[j] = (f32x4){0.f, 0.f, 0.f, 0.f};
  float mrun[4] = {-1e30f, -1e30f, -1e30f, -1e30f};
  float lrun[4] = {0.f, 0.f, 0.f, 0.f};

  int cur = 0;
  STAGE_TILE(0, 0);

  for (int kt = 0; kt <= kthi; ++kt) {
    if (kt < kthi) {
      STAGE_TILE(kt + 1, cur ^ 1);
      asm volatile("s_waitcnt vmcnt(4)" ::: "memory");  // tile kt landed
    } else {
      asm volatile("s_waitcnt vmcnt(0)" ::: "memory");
    }
    __builtin_amdgcn_s_barrier();

    if (kt <= ktwave) {
      const char* Kl = (const char*)Klds + cur * 16384;
      const char* Vl = (const char*)Vlds + cur * 16384;

      f32x4 s[4];
#pragma unroll
      for (int nf = 0; nf < 4; ++nf) s[nf] = (f32x4){0.f, 0.f, 0.f, 0.f};
#pragma unroll
      for (int ks = 0; ks < 4; ++ks) {
#pragma unroll
        for (int nf = 0; nf < 4; ++nf) {
          int row = 16 * nf + r16;
          bf16x8 kf = *(const bf16x8*)(Kl + row * 256 +
                                       (((ks * 4 + g4) ^ (row & 7)) << 4));
          s[nf] = MF(qf[ks], kf, s[nf]);
        }
      }

      const bool diag = (kt == ktwave);
#pragma unroll
      for (int i = 0; i < 4; ++i) {
        int qg = q0 + 16 * w + 4 * g4 + i;
        float sv[4];
        float rmax = -1e30f;
#pragma unroll
        for (int nf = 0; nf < 4; ++nf) {
          float t = s[nf][i];
          if (diag && (kt * 64 + 16 * nf + r16) > qg) t = -1e30f;
          sv[nf] = t;
          rmax = fmaxf(rmax, t);
        }
        rmax = fmaxf(rmax, __shfl_xor(rmax, 1));
        rmax = fmaxf(rmax, __shfl_xor(rmax, 2));
        rmax = fmaxf(rmax, __shfl_xor(rmax, 4));
        rmax = fmaxf(rmax, __shfl_xor(rmax, 8));
        float mnew = fmaxf(mrun[i], rmax);
        float corr = __expf(mrun[i] - mnew);
        mrun[i] = mnew;
        float rs = 0.f;
#pragma unroll
        for (int nf = 0; nf < 4; ++nf) {
          float pv = __expf(sv[nf] - mnew);
          P[w][4 * g4 + i][16 * nf + r16] = f2bf(pv);
          rs += pv;
        }
        rs += __shfl_xor(rs, 1);
        rs += __shfl_xor(rs, 2);
        rs += __shfl_xor(rs, 4);
        rs += __shfl_xor(rs, 8);
        lrun[i] = lrun[i] * corr + rs;
#pragma unroll
        for (int nf2 = 0; nf2 < 8; ++nf2) o[nf2][i] *= corr;
      }
      // P is wave-private: compiler lgkmcnt ordering suffices (no barrier).
#pragma unroll
      for (int ks2 = 0; ks2 < 2; ++ks2) {
        bf16x8 pf = *(const bf16x8*)(&P[w][r16][ks2 * 32 + g4 * 8]);
#pragma unroll
        for (int nf2 = 0; nf2 < 8; ++nf2) {
          int row = 16 * nf2 + r16;
          bf16x8 vf = *(const bf16x8*)(Vl + row * 128 +
                                       (((ks2 * 4 + g4) ^ (row & 7)) << 4));
          o[nf2] = MF(pf, vf, o[nf2]);
        }
      }
    }
    FENCE;
    __builtin_amdgcn_s_barrier();   // all waves done with buf[cur]
    cur ^= 1;
  }
#undef STAGE_TILE

  const int b = bh >> 4, h = bh & 15;
#pragma unroll
  for (int nf2 = 0; nf2 < 8; ++nf2) {
#pragma unroll
    for (int i = 0; i < 4; ++i) {
      long row = (long)b * L + q0 + 16 * w + 4 * g4 + i;
      float v = o[nf2][i] / lrun[i];
      Y[row * 2048 + h * 128 + 16 * nf2 + r16] = f2bf(v);
    }
  }
}

// ---------------------------------------------------------------------------
extern "C" void kernel_launch(void* const* d_in, const int* in_sizes, int n_in,
                              void* d_out, int out_size, void* d_ws,
                              size_t ws_size, hipStream_t stream) {
  const float* x = (const float*)d_in[0];
  const float* wa = (const float*)d_in[1];
  const float* wp = (const float*)d_in[2];
  float* out = (float*)d_out;
  const int B = 2, L = 2048, C = 2048;
  const int M = B * L;  // 4096

  unsigned short* xb = (unsigned short*)d_ws;
  unsigned short* wab = xb + (size_t)M * C;
  unsigned short* wpb = wab + (size_t)3 * C * C;
  unsigned short* Qb = wpb + (size_t)C * C;
  unsigned short* Kb = Qb + (size_t)M * C;
  unsigned short* Vb = Kb + (size_t)M * C;
  unsigned short* Yb = Vb + (size_t)M * C;

  const int n1 = M * C / 4;
  const int n2 = n1 + 3 * C * C / 4;
  const int n4 = n2 + C * C / 4;
  cast_all<<<2048, 256, 0, stream>>>(x, wa, wp, xb, wab, wpb, n1, n2, n4);

  // qkv: 256^2 8-phase, grid 24x16
  gemm8p<1><<<dim3(3 * C / 256, M / 256), 512, 0, stream>>>(
      xb, wab, nullptr, Qb, Kb, Vb, M, 3 * C, C, L);

  // attn: QBLK=128, 8 waves, 512 blocks
  attn_fwd<<<512, 512, 0, stream>>>(Qb, Kb, Vb, Yb, L);

  // proj: 2-phase 128^2, grid 512 blocks
  gemm_bt<0><<<(M / 128) * (C / 128), 256, 0, stream>>>(
      Yb, wpb, out, nullptr, nullptr, nullptr, M, C, C, L, C / 128);
}

// Round 12
// 296.011 us; speedup vs baseline: 1.1683x; 1.1683x over previous
//
#include <hip/hip_runtime.h>

typedef __attribute__((ext_vector_type(8))) short bf16x8;
typedef __attribute__((ext_vector_type(4))) float f32x4;

__device__ __forceinline__ unsigned short f2bf(float f) {
  unsigned int u = __float_as_uint(f);
  u += 0x7FFF + ((u >> 16) & 1);
  return (unsigned short)(u >> 16);
}

__device__ __forceinline__ void gload_lds16(const void* g, void* l) {
  __builtin_amdgcn_global_load_lds(
      (const __attribute__((address_space(1))) unsigned int*)g,
      (__attribute__((address_space(3))) unsigned int*)l,
      16, 0, 0);
}

#define MF(a, b, c) __builtin_amdgcn_mfma_f32_16x16x32_bf16((a), (b), (c), 0, 0, 0)
#define FENCE asm volatile("" ::: "memory")

// ---------------------------------------------------------------------------
// fused cast fp32 -> bf16 for x, w_attn, w_proj in one sweep
// ---------------------------------------------------------------------------
__global__ void cast_all(const float* __restrict__ x,
                         const float* __restrict__ wa,
                         const float* __restrict__ wp,
                         unsigned short* __restrict__ xb,
                         unsigned short* __restrict__ wab,
                         unsigned short* __restrict__ wpb,
                         int n1, int n2, int n4) {
  int stride = gridDim.x * blockDim.x;
  for (int i = blockIdx.x * blockDim.x + threadIdx.x; i < n4; i += stride) {
    const float4* src;
    ushort4* dst;
    int j;
    if (i < n1)      { src = (const float4*)x,  dst = (ushort4*)xb,  j = i; }
    else if (i < n2) { src = (const float4*)wa, dst = (ushort4*)wab, j = i - n1; }
    else             { src = (const float4*)wp, dst = (ushort4*)wpb, j = i - n2; }
    float4 v = src[j];
    ushort4 o;
    o.x = f2bf(v.x); o.y = f2bf(v.y); o.z = f2bf(v.z); o.w = f2bf(v.w);
    dst[j] = o;
  }
}

// ---------------------------------------------------------------------------
// 256x256 8-phase GEMM (round-8 schedule, verbatim — 146us, conflicts 0)
// ---------------------------------------------------------------------------
template<int EPI>
__global__ __launch_bounds__(512, 2)
void gemm8p(const unsigned short* __restrict__ A,
            const unsigned short* __restrict__ Bw,
            float* __restrict__ Cf,
            unsigned short* __restrict__ Qo,
            unsigned short* __restrict__ Ko,
            unsigned short* __restrict__ Vo,
            int M, int N, int K, int Lseq) {
  __shared__ unsigned short lds[2][2][2][8192];  // [A0/B1][dbuf][half][128x64]
  const int tid = threadIdx.x;
  const int lane = tid & 63, w = tid >> 6;
  const int wm = w >> 2, wn = w & 3;
  const int bh = wn >> 1;
  const int bcol = (wn & 1) * 64;
  const int g4 = lane >> 4, r16 = lane & 15;
  const long arow0 = (long)blockIdx.y * 256;
  const long brow0 = (long)blockIdx.x * 256;

#define LDA(db, mf, kk)                                                       \
  (*(const bf16x8*)((const char*)&lds[0][db][wm][0] +                         \
                    (((mf)*16 + r16) << 7) +                                  \
                    ((((kk)*4 + g4) ^ (r16 & 7)) << 4)))
#define LDB(db, nf, kk)                                                       \
  (*(const bf16x8*)((const char*)&lds[1][db][bh][0] +                         \
                    ((bcol + (nf)*16 + r16) << 7) +                           \
                    ((((kk)*4 + g4) ^ (r16 & 7)) << 4)))

#define STG(mat, db, half, kt)                                                \
  do {                                                                        \
    const unsigned short* g_ = (mat) ? Bw : A;                                \
    long r0_ = ((mat) ? brow0 : arow0) + (half)*128;                          \
    int k0_ = (kt) << 6;                                                      \
    _Pragma("unroll")                                                         \
    for (int c_ = 0; c_ < 2; ++c_) {                                          \
      int off_ = (c_ << 13) + (tid << 4);                                     \
      int row_ = off_ >> 7;                                                   \
      int scb_ = ((off_ >> 4) & 7) ^ (row_ & 7);                              \
      gload_lds16(g_ + (r0_ + row_) * (long)K + k0_ + scb_ * 8,               \
                  (char*)&lds[mat][db][half][0] + off_);                      \
    }                                                                         \
  } while (0)

  f32x4 acc[8][4];
#pragma unroll
  for (int i = 0; i < 8; ++i)
#pragma unroll
    for (int j = 0; j < 4; ++j) acc[i][j] = (f32x4){0.f, 0.f, 0.f, 0.f};

  bf16x8 b00, b01, b10, b11, b20, b21, b30, b31;

#define PH(db, q, STAGE_STMT, VMSTMT)                                         \
  do {                                                                        \
    bf16x8 a00 = LDA(db, 2*(q), 0), a01 = LDA(db, 2*(q), 1);                  \
    bf16x8 a10 = LDA(db, 2*(q)+1, 0), a11 = LDA(db, 2*(q)+1, 1);              \
    STAGE_STMT;                                                               \
    VMSTMT;                                                                   \
    FENCE; __builtin_amdgcn_s_barrier(); FENCE;                               \
    __builtin_amdgcn_s_setprio(1);                                            \
    acc[2*(q)][0] = MF(a00, b00, acc[2*(q)][0]);                              \
    acc[2*(q)][0] = MF(a01, b01, acc[2*(q)][0]);                              \
    acc[2*(q)][1] = MF(a00, b10, acc[2*(q)][1]);                              \
    acc[2*(q)][1] = MF(a01, b11, acc[2*(q)][1]);                              \
    acc[2*(q)][2] = MF(a00, b20, acc[2*(q)][2]);                              \
    acc[2*(q)][2] = MF(a01, b21, acc[2*(q)][2]);                              \
    acc[2*(q)][3] = MF(a00, b30, acc[2*(q)][3]);                              \
    acc[2*(q)][3] = MF(a01, b31, acc[2*(q)][3]);                              \
    acc[2*(q)+1][0] = MF(a10, b00, acc[2*(q)+1][0]);                          \
    acc[2*(q)+1][0] = MF(a11, b01, acc[2*(q)+1][0]);                          \
    acc[2*(q)+1][1] = MF(a10, b10, acc[2*(q)+1][1]);                          \
    acc[2*(q)+1][1] = MF(a11, b11, acc[2*(q)+1][1]);                          \
    acc[2*(q)+1][2] = MF(a10, b20, acc[2*(q)+1][2]);                          \
    acc[2*(q)+1][2] = MF(a11, b21, acc[2*(q)+1][2]);                          \
    acc[2*(q)+1][3] = MF(a10, b30, acc[2*(q)+1][3]);                          \
    acc[2*(q)+1][3] = MF(a11, b31, acc[2*(q)+1][3]);                          \
    __builtin_amdgcn_s_setprio(0);                                            \
    FENCE; __builtin_amdgcn_s_barrier(); FENCE;                               \
  } while (0)

#define LOADB(db)                                                             \
  do {                                                                        \
    b00 = LDB(db, 0, 0); b01 = LDB(db, 0, 1);                                 \
    b10 = LDB(db, 1, 0); b11 = LDB(db, 1, 1);                                 \
    b20 = LDB(db, 2, 0); b21 = LDB(db, 2, 1);                                 \
    b30 = LDB(db, 3, 0); b31 = LDB(db, 3, 1);                                 \
  } while (0)

#define VM4 asm volatile("s_waitcnt vmcnt(4)" ::: "memory")

  const int NT = K >> 6;
  STG(0, 0, 0, 0); STG(0, 0, 1, 0);
  STG(1, 0, 0, 0); STG(1, 0, 1, 0);
  STG(1, 1, 0, 1); STG(1, 1, 1, 1);
  VM4;
  FENCE; __builtin_amdgcn_s_barrier(); FENCE;

  for (int i = 0; i < (NT >> 1); ++i) {
    const int t1 = 2 * i + 1;
    int n0 = 2 * i + 2; if (n0 > NT - 1) n0 = NT - 1;
    int n1 = 2 * i + 3; if (n1 > NT - 1) n1 = NT - 1;
    LOADB(0);
    PH(0, 0, STG(0, 1, 0, t1), );        // ph1
    PH(0, 1, STG(0, 1, 1, t1), );        // ph2
    PH(0, 2, STG(1, 0, 0, n0), );        // ph3
    PH(0, 3, STG(1, 0, 1, n0), VM4);     // ph4
    LOADB(1);
    PH(1, 0, STG(0, 0, 0, n0), );        // ph5
    PH(1, 1, STG(0, 0, 1, n0), );        // ph6
    PH(1, 2, STG(1, 1, 0, n1), );        // ph7
    PH(1, 3, STG(1, 1, 1, n1), VM4);     // ph8
  }
  asm volatile("s_waitcnt vmcnt(0)" ::: "memory");

  const float qscale = 0.08838834764831845f;
#pragma unroll
  for (int mf = 0; mf < 8; ++mf) {
#pragma unroll
    for (int nf = 0; nf < 4; ++nf) {
#pragma unroll
      for (int i = 0; i < 4; ++i) {
        long row = arow0 + wm * 128 + mf * 16 + 4 * g4 + i;
        long col = brow0 + wn * 64 + nf * 16 + r16;
        float v = acc[mf][nf][i];
        if (EPI == 0) {
          Cf[row * N + col] = v;
        } else {
          int which = (int)(col >> 11);
          int h = ((int)col >> 7) & 15;
          int d = (int)col & 127;
          int b = (int)(row >> 11);
          int l = (int)row & 2047;
          long bhead = (long)(b * 16 + h);
          if (which == 0)
            Qo[(bhead * Lseq + l) * 128 + d] = f2bf(v * qscale);
          else if (which == 1)
            Ko[(bhead * Lseq + l) * 128 + d] = f2bf(v);
          else
            Vo[(bhead * 128 + d) * Lseq + l] = f2bf(v);
        }
      }
    }
  }
#undef LDA
#undef LDB
#undef STG
#undef PH
#undef LOADB
#undef VM4
}

// ---------------------------------------------------------------------------
// 2-phase 128x128 GEMM (proj). Known-correct.
// ---------------------------------------------------------------------------
template<int EPI>
__global__ __launch_bounds__(256, 4)
void gemm_bt(const unsigned short* __restrict__ A,
             const unsigned short* __restrict__ Bw,
             float* __restrict__ Cf,
             unsigned short* __restrict__ Qo,
             unsigned short* __restrict__ Ko,
             unsigned short* __restrict__ Vo,
             int M, int N, int K, int Lseq, int nbx) {
  __shared__ unsigned short As[2][128 * 32];
  __shared__ unsigned short Bs[2][128 * 32];
  const int tid = threadIdx.x;
  const int lane = tid & 63, w = tid >> 6;
  const int wm = w >> 1, wn = w & 1;
  const int g4 = lane >> 4, r16 = lane & 15;

  const int nwg = gridDim.x;
  const int cpx = nwg >> 3;
  const int bid = (blockIdx.x & 7) * cpx + (blockIdx.x >> 3);
  const long arow0 = (long)(bid / nbx) * 128;
  const long brow0 = (long)(bid % nbx) * 128;

#define STAGE_G(k0_, buf_)                                                    \
  do {                                                                        \
    _Pragma("unroll")                                                         \
    for (int c_ = 0; c_ < 2; ++c_) {                                          \
      int off_ = (w << 11) + (c_ << 10) + (lane << 4);                        \
      int row_ = off_ >> 6;                                                   \
      int cbs_ = ((off_ >> 4) & 3) ^ ((row_ >> 1) & 3);                       \
      gload_lds16(A + (arow0 + row_) * (long)K + (k0_) + cbs_ * 8,            \
                  (char*)As[buf_] + off_);                                    \
      gload_lds16(Bw + (brow0 + row_) * (long)K + (k0_) + cbs_ * 8,           \
                  (char*)Bs[buf_] + off_);                                    \
    }                                                                         \
  } while (0)

  f32x4 acc[4][4];
#pragma unroll
  for (int i = 0; i < 4; ++i)
#pragma unroll
    for (int j = 0; j < 4; ++j) acc[i][j] = (f32x4){0.f, 0.f, 0.f, 0.f};

  const int T = K >> 5;
  int cur = 0;
  STAGE_G(0, 0);

  for (int t = 0; t < T; ++t) {
    if (t < T - 1) {
      STAGE_G((t + 1) << 5, cur ^ 1);
      asm volatile("s_waitcnt vmcnt(4)" ::: "memory");
    } else {
      asm volatile("s_waitcnt vmcnt(0)" ::: "memory");
    }
    __builtin_amdgcn_s_barrier();

    const int rb = g4 ^ ((r16 >> 1) & 3);
    bf16x8 af[4], bf[4];
#pragma unroll
    for (int mf = 0; mf < 4; ++mf)
      af[mf] = *(const bf16x8*)((const char*)As[cur] +
                                ((64 * wm + 16 * mf + r16) << 6) + (rb << 4));
#pragma unroll
    for (int nf = 0; nf < 4; ++nf)
      bf[nf] = *(const bf16x8*)((const char*)Bs[cur] +
                                ((64 * wn + 16 * nf + r16) << 6) + (rb << 4));
#pragma unroll
    for (int mf = 0; mf < 4; ++mf)
#pragma unroll
      for (int nf = 0; nf < 4; ++nf)
        acc[mf][nf] = MF(af[mf], bf[nf], acc[mf][nf]);
    asm volatile("" ::: "memory");
    __builtin_amdgcn_s_barrier();
    cur ^= 1;
  }
#undef STAGE_G

  const float qscale = 0.08838834764831845f;
#pragma unroll
  for (int mf = 0; mf < 4; ++mf) {
#pragma unroll
    for (int nf = 0; nf < 4; ++nf) {
#pragma unroll
      for (int i = 0; i < 4; ++i) {
        long row = arow0 + 64 * wm + 16 * mf + 4 * g4 + i;
        long col = brow0 + 64 * wn + 16 * nf + r16;
        float v = acc[mf][nf][i];
        if (EPI == 0) {
          Cf[row * N + col] = v;
        } else {
          int which = (int)(col >> 11);
          int h = ((int)col >> 7) & 15;
          int d = (int)col & 127;
          int b = (int)(row >> 11);
          int l = (int)row & 2047;
          long bhead = (long)(b * 16 + h);
          if (which == 0)
            Qo[(bhead * Lseq + l) * 128 + d] = f2bf(v * qscale);
          else if (which == 1)
            Ko[(bhead * Lseq + l) * 128 + d] = f2bf(v);
          else
            Vo[(bhead * 128 + d) * Lseq + l] = f2bf(v);
        }
      }
    }
  }
}

// ---------------------------------------------------------------------------
// Flash attention (causal), QBLK=64, 4 waves, 2 blocks/CU (round-6 shell).
// NEW per-wave dataflow: swapped QK^T (mfma(K,Q)) -> S[key][q], q=r16:
// softmax is in-lane over 16 regs + 2 shfl_xor (vs 32 shfl before).
// P^T stored to wave-private LDS [q=r16][k] with XOR swizzle; PV reads it as
// the A-operand (conflict-free b128), producing O in the SAME layout as
// before (q=4g4+i, d=16nf2+r16). corr/lrun cross layouts via tiny LDS
// broadcast. Defer-max (THR=8) skips the O-rescale when max doesn't grow.
// ---------------------------------------------------------------------------
__global__ __launch_bounds__(256, 2)
void attn_fwd(const unsigned short* __restrict__ Q,
              const unsigned short* __restrict__ K,
              const unsigned short* __restrict__ Vt,
              unsigned short* __restrict__ Y, int L) {
  const int D = 128;
  const int id = blockIdx.x;
  const int g = id & 7, kk = id >> 3;
  const int bh = (g << 2) + (kk >> 5);
  const int qt = 31 - (kk & 31);
  const int tid = threadIdx.x, lane = tid & 63, w = tid >> 6;
  const int g4 = lane >> 4, r16 = lane & 15;
  const int q0 = qt * 64;

  __shared__ unsigned short Klds[2 * 64 * 128];   // 2 x 16KB
  __shared__ unsigned short Vlds[2 * 128 * 64];   // 2 x 16KB
  __shared__ unsigned short P[4][16][64];         // wave-private [q][k], 2KB/wave
  __shared__ float corrS[4][16];
  __shared__ float lrunS[4][16];

  const unsigned short* Qh = Q + (long)bh * L * D;
  const unsigned short* Kh = K + (long)bh * L * D;
  const unsigned short* Vh = Vt + (long)bh * D * L;

#define STAGE_TILE(kt_, buf_)                                                 \
  do {                                                                        \
    const int kbase_ = (kt_) * 64;                                            \
    _Pragma("unroll")                                                         \
    for (int r_ = 0; r_ < 4; ++r_) {                                          \
      int off_ = (tid << 4) + (r_ << 12);                                     \
      int krow_ = off_ >> 8, kcb_ = (off_ >> 4) & 15;                         \
      int kcbs_ = kcb_ ^ (krow_ & 7);                                         \
      gload_lds16(Kh + (long)(kbase_ + krow_) * 128 + kcbs_ * 8,              \
                  (char*)Klds + (buf_)*16384 + (w << 10) + (r_ << 12));       \
      int vrow_ = off_ >> 7, vcb_ = (off_ >> 4) & 7;                          \
      int vcbs_ = vcb_ ^ (vrow_ & 7);                                         \
      gload_lds16(Vh + (long)vrow_ * L + kbase_ + vcbs_ * 8,                  \
                  (char*)Vlds + (buf_)*16384 + (w << 10) + (r_ << 12));       \
    }                                                                         \
  } while (0)

  bf16x8 qf[4];
  {
    long qrow = q0 + 16 * w + r16;
#pragma unroll
    for (int ks = 0; ks < 4; ++ks)
      qf[ks] = *(const bf16x8*)(Qh + qrow * D + ks * 32 + g4 * 8);
  }
  f32x4 o[8];
#pragma unroll
  for (int j = 0; j < 8; ++j) o[j] = (f32x4){0.f, 0.f, 0.f, 0.f};
  float mrun = -1e30f, lrun = 0.f;       // for q = q0 + 16w + r16
  const int qg = q0 + 16 * w + r16;
  char* Pl = (char*)&P[w][0][0];

  int cur = 0;
  STAGE_TILE(0, 0);

  for (int kt = 0; kt <= qt; ++kt) {
    if (kt < qt) {
      STAGE_TILE(kt + 1, cur ^ 1);
      asm volatile("s_waitcnt vmcnt(8)" ::: "memory");
    } else {
      asm volatile("s_waitcnt vmcnt(0)" ::: "memory");
    }
    __builtin_amdgcn_s_barrier();

    const char* Kl = (const char*)Klds + cur * 16384;
    const char* Vl = (const char*)Vlds + cur * 16384;

    // QK^T swapped: s[nf] = S[key=16nf+4g4+i][q=r16]
    f32x4 s[4];
#pragma unroll
    for (int nf = 0; nf < 4; ++nf) s[nf] = (f32x4){0.f, 0.f, 0.f, 0.f};
#pragma unroll
    for (int ks = 0; ks < 4; ++ks) {
#pragma unroll
      for (int nf = 0; nf < 4; ++nf) {
        int row = 16 * nf + r16;
        bf16x8 kf = *(const bf16x8*)(Kl + row * 256 +
                                     (((ks * 4 + g4) ^ (row & 7)) << 4));
        s[nf] = MF(kf, qf[ks], s[nf]);
      }
    }

    // mask + in-lane max over the 16 held keys, then cross-g4 reduce
    const bool diag = (kt == qt);
    float rmax = -1e30f;
#pragma unroll
    for (int nf = 0; nf < 4; ++nf)
#pragma unroll
      for (int i = 0; i < 4; ++i) {
        float t = s[nf][i];
        if (diag && (kt * 64 + 16 * nf + 4 * g4 + i) > qg) t = -1e30f;
        s[nf][i] = t;
        rmax = fmaxf(rmax, t);
      }
    rmax = fmaxf(rmax, __shfl_xor(rmax, 16));
    rmax = fmaxf(rmax, __shfl_xor(rmax, 32));

    const bool full = __any(rmax > mrun + 8.0f);   // defer-max
    float corr = 1.f;
    if (full) {
      float mnew = fmaxf(mrun, rmax);
      corr = __expf(mrun - mnew);
      mrun = mnew;
      if (g4 == 0) corrS[w][r16] = corr;
    }

    // P = exp(S - mrun), packed 4xbf16, written transposed to P[q=r16][k]
    float rs = 0.f;
#pragma unroll
    for (int nf = 0; nf < 4; ++nf) {
      float p0 = __expf(s[nf][0] - mrun);
      float p1 = __expf(s[nf][1] - mrun);
      float p2 = __expf(s[nf][2] - mrun);
      float p3 = __expf(s[nf][3] - mrun);
      rs += (p0 + p1) + (p2 + p3);
      ushort4 pw;
      pw.x = f2bf(p0); pw.y = f2bf(p1); pw.z = f2bf(p2); pw.w = f2bf(p3);
      *(ushort4*)(Pl + r16 * 128 + (((2 * nf + (g4 >> 1)) ^ (r16 & 7)) << 4) +
                  ((g4 & 1) << 3)) = pw;
    }
    rs += __shfl_xor(rs, 16);
    rs += __shfl_xor(rs, 32);
    lrun = lrun * corr + rs;

    if (full) {
#pragma unroll
      for (int i = 0; i < 4; ++i) {
        float cb = corrS[w][4 * g4 + i];
#pragma unroll
        for (int nf2 = 0; nf2 < 8; ++nf2) o[nf2][i] *= cb;
      }
    }

    // PV: pf = P^T[q=r16][32ks2+8g4..+7] as A-operand; O layout unchanged
#pragma unroll
    for (int ks2 = 0; ks2 < 2; ++ks2) {
      bf16x8 pf = *(const bf16x8*)(Pl + r16 * 128 +
                                   (((ks2 * 4 + g4) ^ (r16 & 7)) << 4));
#pragma unroll
      for (int nf2 = 0; nf2 < 8; ++nf2) {
        int row = 16 * nf2 + r16;
        bf16x8 vf = *(const bf16x8*)(Vl + row * 128 +
                                     (((ks2 * 4 + g4) ^ (row & 7)) << 4));
        o[nf2] = MF(pf, vf, o[nf2]);
      }
    }
    FENCE;
    __builtin_amdgcn_s_barrier();
    cur ^= 1;
  }
#undef STAGE_TILE

  if (g4 == 0) lrunS[w][r16] = lrun;
  const int b = bh >> 4, h = bh & 15;
#pragma unroll
  for (int i = 0; i < 4; ++i) {
    float linv = 1.f / lrunS[w][4 * g4 + i];
#pragma unroll
    for (int nf2 = 0; nf2 < 8; ++nf2) {
      long row = (long)b * L + q0 + 16 * w + 4 * g4 + i;
      Y[row * 2048 + h * 128 + 16 * nf2 + r16] = f2bf(o[nf2][i] * linv);
    }
  }
}

// ---------------------------------------------------------------------------
extern "C" void kernel_launch(void* const* d_in, const int* in_sizes, int n_in,
                              void* d_out, int out_size, void* d_ws,
                              size_t ws_size, hipStream_t stream) {
  const float* x = (const float*)d_in[0];
  const float* wa = (const float*)d_in[1];
  const float* wp = (const float*)d_in[2];
  float* out = (float*)d_out;
  const int B = 2, L = 2048, C = 2048;
  const int M = B * L;  // 4096

  unsigned short* xb = (unsigned short*)d_ws;
  unsigned short* wab = xb + (size_t)M * C;
  unsigned short* wpb = wab + (size_t)3 * C * C;
  unsigned short* Qb = wpb + (size_t)C * C;
  unsigned short* Kb = Qb + (size_t)M * C;
  unsigned short* Vb = Kb + (size_t)M * C;
  unsigned short* Yb = Vb + (size_t)M * C;

  const int n1 = M * C / 4;
  const int n2 = n1 + 3 * C * C / 4;
  const int n4 = n2 + C * C / 4;
  cast_all<<<2048, 256, 0, stream>>>(x, wa, wp, xb, wab, wpb, n1, n2, n4);

  // qkv: 256^2 8-phase, grid 24x16
  gemm8p<1><<<dim3(3 * C / 256, M / 256), 512, 0, stream>>>(
      xb, wab, nullptr, Qb, Kb, Vb, M, 3 * C, C, L);

  // attn: QBLK=64, 4 waves, 1024 blocks (2 blocks/CU)
  attn_fwd<<<1024, 256, 0, stream>>>(Qb, Kb, Vb, Yb, L);

  // proj: 2-phase 128^2, grid 512 blocks
  gemm_bt<0><<<(M / 128) * (C / 128), 256, 0, stream>>>(
      Yb, wpb, out, nullptr, nullptr, nullptr, M, C, C, L, C / 128);
}